// Round 1
// baseline (331.281 us; speedup 1.0000x reference)
//
#include <hip/hip_runtime.h>

#define NB 2048
#define NM 128
#define ND 5
#define NFA 62
#define NFB 6
#define NFAN 68
#define NC 128
#define LDF 68   // LDS row stride (floats); 68*4=272B, 16B aligned, bank phase 4e

__global__ __launch_bounds__(256) void tga_fused(
    const float* __restrict__ atoms,
    const float* __restrict__ bonds,
    const int*   __restrict__ edges,
    const float* __restrict__ W_inner,
    const float* __restrict__ b_inner,
    const float* __restrict__ W_self,
    const float* __restrict__ b_self,
    float* __restrict__ out)
{
    __shared__ __align__(16) float s_vx[NM * LDF];  // [atoms | summed_bonds] = vxi rows
    __shared__ __align__(16) float s_sf[NM * LDF];  // [summed_atoms | summed_bonds]
    __shared__ int s_list[NM];                      // rows with deg<5: m | (deg<<16)
    __shared__ int s_nlist;

    const int tid = threadIdx.x;
    const int b   = blockIdx.x;

    if (tid == 0) s_nlist = 0;

    // ---- Phase 0: stage atoms[b] into s_vx cols [0,62) ----
    const float* atoms_b = atoms + (size_t)b * (NM * NFA);
    for (int i = tid; i < NM * NFA; i += 256) {
        int m = i / NFA;
        int f = i - m * NFA;
        s_vx[m * LDF + f] = atoms_b[i];
    }
    __syncthreads();

    // ---- Phase 1: per-row degree, neighbor-atom sums, bond sums ----
    {
        const int m    = tid >> 1;
        const int half = tid & 1;
        const int* e = edges + ((size_t)b * NM + m) * ND;
        const int e0 = e[0], e1 = e[1], e2 = e[2], e3 = e[3], e4 = e[4];

        if (half == 0) {
            const int deg = (e0 >= 0) + (e1 >= 0) + (e2 >= 0) + (e3 >= 0) + (e4 >= 0);
            if (deg < ND) {
                int slot = atomicAdd(&s_nlist, 1);
                s_list[slot] = m | (deg << 16);
            }
        }

        // summed_atoms: half0 does quads f=0..28 (cols 0..31), half1 quads f=32..60
        // (cols 32..63; cols 62,63 are garbage reads/writes, overwritten below by
        // this same thread's bond-sum store -> program order safe).
        const int q0 = half * 8;
        #pragma unroll
        for (int q = 0; q < 8; ++q) {
            const int f = 4 * (q0 + q);
            float4 acc = make_float4(0.f, 0.f, 0.f, 0.f);
            if (e0 >= 0) { float4 v = *(const float4*)&s_vx[e0 * LDF + f]; acc.x += v.x; acc.y += v.y; acc.z += v.z; acc.w += v.w; }
            if (e1 >= 0) { float4 v = *(const float4*)&s_vx[e1 * LDF + f]; acc.x += v.x; acc.y += v.y; acc.z += v.z; acc.w += v.w; }
            if (e2 >= 0) { float4 v = *(const float4*)&s_vx[e2 * LDF + f]; acc.x += v.x; acc.y += v.y; acc.z += v.z; acc.w += v.w; }
            if (e3 >= 0) { float4 v = *(const float4*)&s_vx[e3 * LDF + f]; acc.x += v.x; acc.y += v.y; acc.z += v.z; acc.w += v.w; }
            if (e4 >= 0) { float4 v = *(const float4*)&s_vx[e4 * LDF + f]; acc.x += v.x; acc.y += v.y; acc.z += v.z; acc.w += v.w; }
            *(float4*)&s_sf[m * LDF + f] = acc;
        }

        if (half == 1) {
            // bond sums: 30 contiguous floats per row, float2 loads (base 120B -> 8B aligned)
            const float* bp = bonds + ((size_t)b * NM + m) * (ND * NFB);
            float sb[NFB] = {0.f, 0.f, 0.f, 0.f, 0.f, 0.f};
            #pragma unroll
            for (int p = 0; p < 15; ++p) {
                float2 v = *(const float2*)&bp[2 * p];
                sb[(2 * p) % NFB]     += v.x;
                sb[(2 * p + 1) % NFB] += v.y;
            }
            #pragma unroll
            for (int j = 0; j < NFB; ++j) {
                s_vx[m * LDF + NFA + j] = sb[j];
                s_sf[m * LDF + NFA + j] = sb[j];
            }
        }
    }
    __syncthreads();

    // ---- Phase 2: self matvec, zxi = relu(vx @ W_self + b_self) ----
    const int c  = tid & 127;
    const int rg = tid >> 7;

    float w[NFAN];
    #pragma unroll
    for (int f = 0; f < NFAN; ++f) w[f] = W_self[f * NC + c];
    const float bs = b_self[c];

    float* out_b = out + (size_t)b * (NM * NC);

    #pragma unroll
    for (int chunk = 0; chunk < 4; ++chunk) {
        const int m0 = rg * 64 + chunk * 16;
        float acc[16];
        #pragma unroll
        for (int r = 0; r < 16; ++r) acc[r] = bs;
        #pragma unroll
        for (int q = 0; q < 17; ++q) {
            #pragma unroll
            for (int r = 0; r < 16; ++r) {
                float4 v = *(const float4*)&s_vx[(m0 + r) * LDF + 4 * q];
                acc[r] += v.x * w[4 * q] + v.y * w[4 * q + 1] + v.z * w[4 * q + 2] + v.w * w[4 * q + 3];
            }
        }
        #pragma unroll
        for (int r = 0; r < 16; ++r) {
            out_b[(m0 + r) * NC + c] = fmaxf(acc[r], 0.0f);
        }
    }
    __syncthreads();

    // ---- Phase 3: inner matvec only for rows with deg<5 (~5 rows/block) ----
    const int nl = s_nlist;
    for (int base = 0; base < nl; base += 32) {
        #pragma unroll 1
        for (int r = 0; r < 16; ++r) {
            const int i2 = base + rg * 16 + r;
            if (i2 < nl) {
                const int packed = s_list[i2];
                const int m = packed & 0xFFFF;
                const int d = packed >> 16;
                const float* Wd = W_inner + (size_t)d * (NFAN * NC);
                float acc = b_inner[d * NC + c];
                #pragma unroll
                for (int q = 0; q < 17; ++q) {
                    float4 v = *(const float4*)&s_sf[m * LDF + 4 * q];
                    acc += v.x * Wd[(4 * q) * NC + c] + v.y * Wd[(4 * q + 1) * NC + c]
                         + v.z * Wd[(4 * q + 2) * NC + c] + v.w * Wd[(4 * q + 3) * NC + c];
                }
                out_b[m * NC + c] += fmaxf(acc, 0.0f);
            }
        }
    }
}

extern "C" void kernel_launch(void* const* d_in, const int* in_sizes, int n_in,
                              void* d_out, int out_size, void* d_ws, size_t ws_size,
                              hipStream_t stream) {
    const float* atoms   = (const float*)d_in[0];
    const float* bonds   = (const float*)d_in[1];
    const int*   edges   = (const int*)d_in[2];
    const float* W_inner = (const float*)d_in[3];
    const float* b_inner = (const float*)d_in[4];
    const float* W_self  = (const float*)d_in[5];
    const float* b_self  = (const float*)d_in[6];
    float* out = (float*)d_out;

    tga_fused<<<NB, 256, 0, stream>>>(atoms, bonds, edges, W_inner, b_inner,
                                      W_self, b_self, out);
}

// Round 2
// 268.421 us; speedup vs baseline: 1.2342x; 1.2342x over previous
//
#include <hip/hip_runtime.h>

#define NB 2048
#define NM 128
#define ND 5
#define NFA 62
#define NFB 6
#define NFAN 68
#define NC 128
#define LDA 104     // bf16 row stride for s_A/s_B: 208 B, 52-bank phase -> conflict-free mfma frag reads
#define LDSF 72     // fp32 row stride for s_sf
#define CHUNK 32

typedef __bf16 bf16x8 __attribute__((ext_vector_type(8)));
typedef float floatx4 __attribute__((ext_vector_type(4)));

__device__ __forceinline__ unsigned short f2bf(float x) {
    unsigned u = __builtin_bit_cast(unsigned, x);
    u += 0x7FFFu + ((u >> 16) & 1u);   // RNE
    return (unsigned short)(u >> 16);
}

__global__ __launch_bounds__(256) void tga_mfma(
    const float* __restrict__ atoms,
    const float* __restrict__ bonds,
    const int*   __restrict__ edges,
    const float* __restrict__ W_inner,
    const float* __restrict__ b_inner,
    const float* __restrict__ W_self,
    const float* __restrict__ b_self,
    float* __restrict__ out)
{
    __shared__ __align__(16) unsigned short s_A[NM * LDA];  // vxi rows in bf16, K-padded with zeros
    __shared__ __align__(16) unsigned short s_B[NC * LDA];  // W_self^T in bf16 [c][k], K-padded
    __shared__ __align__(16) float s_sf[CHUNK * LDSF];      // summed features, listed rows only
    __shared__ int s_list[NM];
    __shared__ int s_nlist;

    const int tid = threadIdx.x;
    const int b   = blockIdx.x;
    if (tid == 0) s_nlist = 0;

    const float* atoms_b = atoms + (size_t)b * (NM * NFA);
    const int*   edges_b = edges + (size_t)b * (NM * ND);
    const float* bonds_b = bonds + (size_t)b * (NM * ND * NFB);
    float*       out_b   = out   + (size_t)b * (NM * NC);

    // ---- Phase 0a: atoms -> s_A bf16 (cols 0..61), coalesced float2 reads ----
    for (int i = tid; i < NM * 31; i += 256) {
        int m = i / 31, p = i - m * 31;
        float2 v = *(const float2*)&atoms_b[m * NFA + 2 * p];
        unsigned pack = (unsigned)f2bf(v.x) | ((unsigned)f2bf(v.y) << 16);
        *(unsigned*)&s_A[m * LDA + 2 * p] = pack;
    }
    // zero K-pad region s_A[m][68..95]
    for (int i = tid; i < NM * 7; i += 256) {
        int m = i / 7, q = i - m * 7;
        *(unsigned long long*)&s_A[m * LDA + 68 + 4 * q] = 0ULL;
    }
    // ---- Phase 0b: W_self -> s_B transposed bf16 [c][k] ----
    for (int i = tid; i < NFAN * NC; i += 256) {
        int f = i >> 7, c2 = i & 127;
        s_B[c2 * LDA + f] = f2bf(W_self[i]);
    }
    for (int i = tid; i < NC * 7; i += 256) {
        int c2 = i / 7, q = i - c2 * 7;
        *(unsigned long long*)&s_B[c2 * LDA + 68 + 4 * q] = 0ULL;
    }

    // ---- Phase 1: degree/list + bond sums (bf16 into s_A cols 62..67) ----
    {
        const int m = tid >> 1, half = tid & 1;
        if (half == 0) {
            const int* e = edges_b + m * ND;
            int deg = 0;
            #pragma unroll
            for (int j = 0; j < ND; ++j) deg += (e[j] >= 0);
            if (deg < ND) {
                int slot = atomicAdd(&s_nlist, 1);
                s_list[slot] = m | (deg << 16);
            }
        } else {
            const float* bp = bonds_b + m * (ND * NFB);
            float sb[NFB] = {0.f, 0.f, 0.f, 0.f, 0.f, 0.f};
            #pragma unroll
            for (int p = 0; p < 15; ++p) {
                float2 v = *(const float2*)&bp[2 * p];
                sb[(2 * p) % NFB]     += v.x;
                sb[(2 * p + 1) % NFB] += v.y;
            }
            *(unsigned*)&s_A[m * LDA + 62] = (unsigned)f2bf(sb[0]) | ((unsigned)f2bf(sb[1]) << 16);
            *(unsigned*)&s_A[m * LDA + 64] = (unsigned)f2bf(sb[2]) | ((unsigned)f2bf(sb[3]) << 16);
            *(unsigned*)&s_A[m * LDA + 66] = (unsigned)f2bf(sb[4]) | ((unsigned)f2bf(sb[5]) << 16);
        }
    }
    __syncthreads();

    // ---- Phase 2: zxi = relu(vxi @ W_self + b_self) via MFMA 16x16x32 bf16 ----
    {
        const int lane = tid & 63;
        const int wave = tid >> 6;
        const int col  = lane & 15;   // A-row-in-tile / B-col-in-tile / C-col
        const int quad = lane >> 4;
        const int m0   = wave * 32;

        float bias[8];
        #pragma unroll
        for (int nt = 0; nt < 8; ++nt) bias[nt] = b_self[nt * 16 + col];

        floatx4 acc[16];
        #pragma unroll
        for (int t = 0; t < 16; ++t) {
            floatx4 v; v[0] = v[1] = v[2] = v[3] = bias[t & 7];
            acc[t] = v;
        }

        #pragma unroll
        for (int k = 0; k < 3; ++k) {
            const int koff = k * 32 + quad * 8;
            bf16x8 a0 = *(const bf16x8*)&s_A[(m0 + col) * LDA + koff];
            bf16x8 a1 = *(const bf16x8*)&s_A[(m0 + 16 + col) * LDA + koff];
            #pragma unroll
            for (int nt = 0; nt < 8; ++nt) {
                bf16x8 bf = *(const bf16x8*)&s_B[(nt * 16 + col) * LDA + koff];
                acc[nt]     = __builtin_amdgcn_mfma_f32_16x16x32_bf16(a0, bf, acc[nt],     0, 0, 0);
                acc[8 + nt] = __builtin_amdgcn_mfma_f32_16x16x32_bf16(a1, bf, acc[8 + nt], 0, 0, 0);
            }
        }

        // epilogue: C layout col=lane&15, row=quad*4+reg
        #pragma unroll
        for (int mt = 0; mt < 2; ++mt) {
            #pragma unroll
            for (int nt = 0; nt < 8; ++nt) {
                #pragma unroll
                for (int r = 0; r < 4; ++r) {
                    int m = m0 + mt * 16 + quad * 4 + r;
                    out_b[m * NC + nt * 16 + col] = fmaxf(acc[mt * 8 + nt][r], 0.0f);
                }
            }
        }
    }
    __syncthreads();

    // ---- Phase 3: zni for rows with deg<5 (~5/block), fp32, chunked ----
    const int nl = s_nlist;
    const int c  = tid & 127;
    const int rg = tid >> 7;

    for (int base = 0; base < nl; base += CHUNK) {
        // gather summed features into s_sf (2 threads per listed row, global reads are L1/L2-hot)
        if (tid < 2 * CHUNK) {
            const int r = tid >> 1, half = tid & 1;
            if (base + r < nl) {
                const int m = s_list[base + r] & 0xFFFF;
                const int* e = edges_b + m * ND;
                int ev[ND];
                #pragma unroll
                for (int j = 0; j < ND; ++j) ev[j] = e[j];

                if (half == 0) {
                    float v[32];
                    #pragma unroll
                    for (int j = 0; j < 32; ++j) v[j] = 0.f;
                    #pragma unroll
                    for (int j = 0; j < ND; ++j) {
                        if (ev[j] >= 0) {
                            const float* ap = atoms_b + ev[j] * NFA;
                            #pragma unroll
                            for (int p = 0; p < 16; ++p) {
                                float2 t = *(const float2*)&ap[2 * p];
                                v[2 * p] += t.x; v[2 * p + 1] += t.y;
                            }
                        }
                    }
                    #pragma unroll
                    for (int q = 0; q < 8; ++q)
                        *(float4*)&s_sf[r * LDSF + 4 * q] = make_float4(v[4*q], v[4*q+1], v[4*q+2], v[4*q+3]);
                } else {
                    float v[36];  // features 32..67
                    #pragma unroll
                    for (int j = 0; j < 30; ++j) v[j] = 0.f;
                    #pragma unroll
                    for (int j = 0; j < ND; ++j) {
                        if (ev[j] >= 0) {
                            const float* ap = atoms_b + ev[j] * NFA;
                            #pragma unroll
                            for (int p = 0; p < 15; ++p) {
                                float2 t = *(const float2*)&ap[32 + 2 * p];
                                v[2 * p] += t.x; v[2 * p + 1] += t.y;
                            }
                        }
                    }
                    const float* bp = bonds_b + m * (ND * NFB);
                    float sb[NFB] = {0.f, 0.f, 0.f, 0.f, 0.f, 0.f};
                    #pragma unroll
                    for (int p = 0; p < 15; ++p) {
                        float2 t = *(const float2*)&bp[2 * p];
                        sb[(2 * p) % NFB]     += t.x;
                        sb[(2 * p + 1) % NFB] += t.y;
                    }
                    #pragma unroll
                    for (int j = 0; j < NFB; ++j) v[30 + j] = sb[j];
                    #pragma unroll
                    for (int q = 0; q < 9; ++q)
                        *(float4*)&s_sf[r * LDSF + 32 + 4 * q] = make_float4(v[4*q], v[4*q+1], v[4*q+2], v[4*q+3]);
                }
            }
        }
        __syncthreads();

        const int nrows = min(nl - base, CHUNK);
        for (int r = rg; r < nrows; r += 2) {
            const int packed = s_list[base + r];
            const int m = packed & 0xFFFF;
            const int d = packed >> 16;
            const float* Wd = W_inner + (size_t)d * (NFAN * NC) + c;
            float acc1 = b_inner[d * NC + c];
            #pragma unroll
            for (int q = 0; q < 17; ++q) {
                float4 v = *(const float4*)&s_sf[r * LDSF + 4 * q];
                acc1 += v.x * Wd[(4 * q) * NC] + v.y * Wd[(4 * q + 1) * NC]
                      + v.z * Wd[(4 * q + 2) * NC] + v.w * Wd[(4 * q + 3) * NC];
            }
            out_b[m * NC + c] += fmaxf(acc1, 0.0f);
        }
        __syncthreads();
    }
}

extern "C" void kernel_launch(void* const* d_in, const int* in_sizes, int n_in,
                              void* d_out, int out_size, void* d_ws, size_t ws_size,
                              hipStream_t stream) {
    const float* atoms   = (const float*)d_in[0];
    const float* bonds   = (const float*)d_in[1];
    const int*   edges   = (const int*)d_in[2];
    const float* W_inner = (const float*)d_in[3];
    const float* b_inner = (const float*)d_in[4];
    const float* W_self  = (const float*)d_in[5];
    const float* b_self  = (const float*)d_in[6];
    float* out = (float*)d_out;

    tga_mfma<<<NB, 256, 0, stream>>>(atoms, bonds, edges, W_inner, b_inner,
                                     W_self, b_self, out);
}